// Round 1
// baseline (160.846 us; speedup 1.0000x reference)
//
#include <hip/hip_runtime.h>
#include <hip/hip_cooperative_groups.h>
#include <math.h>

namespace cg = cooperative_groups;

#define EPSF 1e-8f

// float atomic max via int punning (standard trick, handles mixed signs)
__device__ __forceinline__ void atomicMaxFloat(float* addr, float val) {
    if (val >= 0.f) atomicMax((int*)addr, __float_as_int(val));
    else            atomicMin((unsigned int*)addr, __float_as_uint(val));
}

// ---------------------------------------------------------------------------
// Kernel A: small GEMMs (hf = cities@Wf, htT = (cities@Wt)^T, hg = groups@Wg)
// plus zero/init of the global accumulators.
//   blocks 0..127   : hf + htT   (32768 threads: one (b,f,e) each)
//   blocks 128..135 : hg         (2048 threads)
//   block  136      : zero S[10][4][128], init Mdep(32)+Moth(512) to -inf
// ---------------------------------------------------------------------------
__global__ __launch_bounds__(256) void prep_kernel(
        const float* __restrict__ cities, const float* __restrict__ groups,
        const float* __restrict__ W1,
        float* __restrict__ hg, float* __restrict__ hf, float* __restrict__ htT,
        float* __restrict__ S, float* __restrict__ Mbuf) {
    int blk = blockIdx.x, tid = threadIdx.x;
    if (blk < 128) {
        int gid = blk * 256 + tid;          // 0..32767
        int e = gid & 63;
        int f = (gid >> 6) & 127;
        int b = gid >> 13;
        const float* crow = cities + (b * 128 + f) * 64;
        float af = 0.f, at = 0.f;
        #pragma unroll 8
        for (int d = 0; d < 64; ++d) {
            float c = crow[d];                        // wave-uniform (broadcast)
            af = fmaf(c, W1[(64  + d) * 64 + e], af); // coalesced over e
            at = fmaf(c, W1[(128 + d) * 64 + e], at);
        }
        hf [(b * 128 + f) * 64 + e] = af;   // [b][f][e]
        htT[(b * 64  + e) * 128 + f] = at;  // [b][e][t]  (transposed for kernel B)
    } else if (blk < 136) {
        int gid = (blk - 128) * 256 + tid;  // 0..2047
        int e = gid & 63;
        int m = (gid >> 6) & 7;
        int b = gid >> 9;
        const float* grow = groups + (b * 8 + m) * 64;
        float a = 0.f;
        #pragma unroll 8
        for (int d = 0; d < 64; ++d)
            a = fmaf(grow[d], W1[d * 64 + e], a);
        hg[(b * 8 + m) * 64 + e] = a;
    } else {
        for (int i = tid; i < 5120; i += 256) S[i] = 0.f;
        for (int i = tid; i < 544;  i += 256) Mbuf[i] = -INFINITY;
    }
}

// ---------------------------------------------------------------------------
// Kernel B: out[b,m,f,t] = b2 + sum_e W2[e]*relu(hg[bm,e]+hf[bf,e]+ht[bt,e]+b1[e])
// One block per row (b,m,f): 4096 blocks x 128 threads (thread = t).
// Also computes the exp-stabilization maxes:
//   f==0 : per-(b,m) max over t           -> Mdep[b*8+m]
//   f>=1 : per-(b,f) max over (m,t)       -> Moth[b*128+f]
// ---------------------------------------------------------------------------
__global__ __launch_bounds__(128) void mlp_kernel(
        const float* __restrict__ hg, const float* __restrict__ hf,
        const float* __restrict__ htT,
        const float* __restrict__ b1, const float* __restrict__ W2,
        const float* __restrict__ b2,
        float* __restrict__ X, float* __restrict__ Mdep, float* __restrict__ Moth) {
    int r = blockIdx.x;                    // 0..4095 = ((b*8+m)*128+f)
    int f = r & 127, m = (r >> 7) & 7, b = r >> 10;
    int t = threadIdx.x;                   // 0..127
    __shared__ float arow[64], w2s[64];
    if (t < 64) {
        arow[t] = hg[(b * 8 + m) * 64 + t] + hf[(b * 128 + f) * 64 + t] + b1[t];
        w2s[t]  = W2[t];
    }
    __syncthreads();
    const float* htb = htT + b * 8192;     // [e][t] slice for this b
    float acc = 0.f;
    #pragma unroll 16
    for (int e = 0; e < 64; ++e) {
        float v = arow[e] + htb[e * 128 + t];   // coalesced over t
        acc = fmaf(fmaxf(v, 0.f), w2s[e], acc);
    }
    float out = acc + b2[0];
    X[r * 128 + t] = out;

    // block max over 128 threads (2 waves)
    float mx = out;
    #pragma unroll
    for (int off = 32; off; off >>= 1) mx = fmaxf(mx, __shfl_down(mx, off));
    __shared__ float wm[2];
    if ((t & 63) == 0) wm[t >> 6] = mx;
    __syncthreads();
    if (t == 0) {
        float bm = fmaxf(wm[0], wm[1]);
        if (f == 0) atomicMaxFloat(&Mdep[b * 8 + m], bm);
        else        atomicMaxFloat(&Moth[b * 128 + f], bm);
    }
}

// ---------------------------------------------------------------------------
// Kernel C (cooperative): exp(x - max), then 10 alternating normalizations.
// 32 blocks (one per (b,m), full 128x128 tile) x 1024 threads; each thread
// holds a 4x4 register tile. swapaxes handled logically:
//   even k: row-normalize   (f==0 per-(b,m) local; f>=1 per-(b,f) via atomics)
//   odd  k: col-normalize   (t==0 per-(b,m) local; t>=1 per-(b,t) via atomics)
// One grid.sync() per iteration. In-place on d_out.
// ---------------------------------------------------------------------------
__global__ __launch_bounds__(1024) void softassign_kernel(
        float* __restrict__ X, const float* __restrict__ Mdep,
        const float* __restrict__ Moth, float* __restrict__ S) {
    cg::grid_group grid = cg::this_grid();
    int blk = blockIdx.x;                  // 0..31 == b*8+m
    int b = blk >> 3;
    int tid = threadIdx.x;
    int tf = tid >> 5, tt = tid & 31;      // 32x32 thread grid, 4x4 tiles
    float* base = X + blk * 16384;

    float x[4][4];
    #pragma unroll
    for (int r = 0; r < 4; ++r) {
        float4 v = *(const float4*)(base + (4 * tf + r) * 128 + 4 * tt);
        x[r][0] = v.x; x[r][1] = v.y; x[r][2] = v.z; x[r][3] = v.w;
    }

    // exp(x - groupmax)
    float mdep = Mdep[blk];
    #pragma unroll
    for (int r = 0; r < 4; ++r) {
        int f = 4 * tf + r;
        float M = (f == 0) ? mdep : Moth[b * 128 + f];
        #pragma unroll
        for (int c = 0; c < 4; ++c) x[r][c] = expf(x[r][c] - M);
    }

    __shared__ float part[128][33];        // +1 pad: conflict-free reduce
    __shared__ float dnm[128];
    __shared__ float depot;

    for (int k = 0; k < 10; ++k) {
        // clamp (reference: maximum(output, EPS) BEFORE the sums)
        #pragma unroll
        for (int r = 0; r < 4; ++r)
            #pragma unroll
            for (int c = 0; c < 4; ++c) x[r][c] = fmaxf(x[r][c], EPSF);

        int dir = k & 1;
        if (dir == 0) {      // per-row partials: part[f][tt]
            #pragma unroll
            for (int r = 0; r < 4; ++r)
                part[4 * tf + r][tt] = x[r][0] + x[r][1] + x[r][2] + x[r][3];
        } else {             // per-col partials: part[t][tf]
            #pragma unroll
            for (int c = 0; c < 4; ++c)
                part[4 * tt + c][tf] = x[0][c] + x[1][c] + x[2][c] + x[3][c];
        }
        __syncthreads();
        if (tid < 128) {     // reduce 32 partials; tid = f (even k) or t (odd k)
            float s = 0.f;
            #pragma unroll 8
            for (int j = 0; j < 32; ++j) s += part[tid][j];
            if (tid == 0) depot = s;                       // block-local group
            else atomicAdd(&S[(k * 4 + b) * 128 + tid], s); // cross-block (over m)
        }
        grid.sync();

        // stage denominators to LDS (scoped atomic loads bypass stale caches)
        if (tid < 128) {
            dnm[tid] = (tid == 0) ? depot
                : __hip_atomic_load(&S[(k * 4 + b) * 128 + tid],
                                    __ATOMIC_RELAXED, __HIP_MEMORY_SCOPE_AGENT);
        }
        __syncthreads();

        if (dir == 0) {
            #pragma unroll
            for (int r = 0; r < 4; ++r) {
                float inv = 1.f / dnm[4 * tf + r];
                #pragma unroll
                for (int c = 0; c < 4; ++c) x[r][c] *= inv;
            }
        } else {
            #pragma unroll
            for (int c = 0; c < 4; ++c) {
                float inv = 1.f / dnm[4 * tt + c];
                #pragma unroll
                for (int r = 0; r < 4; ++r) x[r][c] *= inv;
            }
        }
    }

    #pragma unroll
    for (int r = 0; r < 4; ++r) {
        float4 v = make_float4(x[r][0], x[r][1], x[r][2], x[r][3]);
        *(float4*)(base + (4 * tf + r) * 128 + 4 * tt) = v;
    }
}

// ---------------------------------------------------------------------------
extern "C" void kernel_launch(void* const* d_in, const int* in_sizes, int n_in,
                              void* d_out, int out_size, void* d_ws, size_t ws_size,
                              hipStream_t stream) {
    const float* cities = (const float*)d_in[0];  // (4,128,64)
    const float* groups = (const float*)d_in[1];  // (4,8,64)
    const float* W1     = (const float*)d_in[2];  // (192,64)
    const float* b1     = (const float*)d_in[3];  // (64,)
    const float* W2     = (const float*)d_in[4];  // (64,1)
    const float* b2     = (const float*)d_in[5];  // (1,)
    float* X  = (float*)d_out;                    // (4,8,128,128) — also scratch
    float* ws = (float*)d_ws;

    float* hg   = ws;            // 2048
    float* hf   = ws + 2048;     // 32768
    float* htT  = ws + 34816;    // 32768
    float* S    = ws + 67584;    // 10*4*128 = 5120
    float* Mbuf = ws + 72704;    // Mdep(32) | Moth(512)
    float* Mdep = Mbuf;
    float* Moth = Mbuf + 32;

    prep_kernel<<<137, 256, 0, stream>>>(cities, groups, W1, hg, hf, htT, S, Mbuf);
    mlp_kernel<<<4096, 128, 0, stream>>>(hg, hf, htT, b1, W2, b2, X, Mdep, Moth);

    void* args[] = { (void*)&X, (void*)&Mdep, (void*)&Moth, (void*)&S };
    hipLaunchCooperativeKernel((void*)softassign_kernel, dim3(32), dim3(1024),
                               args, 0, stream);
}

// Round 2
// 105.576 us; speedup vs baseline: 1.5235x; 1.5235x over previous
//
#include <hip/hip_runtime.h>
#include <math.h>

#define EPSF 1e-8f

// float atomic max via int punning (standard trick, handles mixed signs)
__device__ __forceinline__ void atomicMaxFloat(float* addr, float val) {
    if (val >= 0.f) atomicMax((int*)addr, __float_as_int(val));
    else            atomicMin((unsigned int*)addr, __float_as_uint(val));
}

// ---------------------------------------------------------------------------
// Kernel A: small GEMMs (hf = cities@Wf, htT = (cities@Wt)^T, hg = groups@Wg)
// plus zero/init of the global accumulators + barrier counters.
//   blocks 0..127   : hf + htT   (32768 threads: one (b,f,e) each)
//   blocks 128..135 : hg         (2048 threads)
//   block  136      : zero S[10][4][128], cnt[40]; init Mdep(32)+Moth(512)=-inf
// ---------------------------------------------------------------------------
__global__ __launch_bounds__(256) void prep_kernel(
        const float* __restrict__ cities, const float* __restrict__ groups,
        const float* __restrict__ W1,
        float* __restrict__ hg, float* __restrict__ hf, float* __restrict__ htT,
        float* __restrict__ S, float* __restrict__ Mbuf,
        unsigned* __restrict__ cnt) {
    int blk = blockIdx.x, tid = threadIdx.x;
    if (blk < 128) {
        int gid = blk * 256 + tid;          // 0..32767
        int e = gid & 63;
        int f = (gid >> 6) & 127;
        int b = gid >> 13;
        const float* crow = cities + (b * 128 + f) * 64;
        float af = 0.f, at = 0.f;
        #pragma unroll 8
        for (int d = 0; d < 64; ++d) {
            float c = crow[d];                        // wave-uniform (broadcast)
            af = fmaf(c, W1[(64  + d) * 64 + e], af); // coalesced over e
            at = fmaf(c, W1[(128 + d) * 64 + e], at);
        }
        hf [(b * 128 + f) * 64 + e] = af;   // [b][f][e]
        htT[(b * 64  + e) * 128 + f] = at;  // [b][e][t]  (transposed for kernel B)
    } else if (blk < 136) {
        int gid = (blk - 128) * 256 + tid;  // 0..2047
        int e = gid & 63;
        int m = (gid >> 6) & 7;
        int b = gid >> 9;
        const float* grow = groups + (b * 8 + m) * 64;
        float a = 0.f;
        #pragma unroll 8
        for (int d = 0; d < 64; ++d)
            a = fmaf(grow[d], W1[d * 64 + e], a);
        hg[(b * 8 + m) * 64 + e] = a;
    } else {
        for (int i = tid; i < 5120; i += 256) S[i] = 0.f;
        for (int i = tid; i < 544;  i += 256) Mbuf[i] = -INFINITY;
        if (tid < 40) cnt[tid] = 0u;
    }
}

// ---------------------------------------------------------------------------
// Kernel B: out[b,m,f,t] = b2 + sum_e W2[e]*relu(hg[bm,e]+hf[bf,e]+ht[bt,e]+b1[e])
// One block per row (b,m,f): 4096 blocks x 128 threads (thread = t).
// Also computes the exp-stabilization maxes:
//   f==0 : per-(b,m) max over t           -> Mdep[b*8+m]
//   f>=1 : per-(b,f) max over (m,t)       -> Moth[b*128+f]
// ---------------------------------------------------------------------------
__global__ __launch_bounds__(128) void mlp_kernel(
        const float* __restrict__ hg, const float* __restrict__ hf,
        const float* __restrict__ htT,
        const float* __restrict__ b1, const float* __restrict__ W2,
        const float* __restrict__ b2,
        float* __restrict__ X, float* __restrict__ Mdep, float* __restrict__ Moth) {
    int r = blockIdx.x;                    // 0..4095 = ((b*8+m)*128+f)
    int f = r & 127, m = (r >> 7) & 7, b = r >> 10;
    int t = threadIdx.x;                   // 0..127
    __shared__ float arow[64], w2s[64];
    if (t < 64) {
        arow[t] = hg[(b * 8 + m) * 64 + t] + hf[(b * 128 + f) * 64 + t] + b1[t];
        w2s[t]  = W2[t];
    }
    __syncthreads();
    const float* htb = htT + b * 8192;     // [e][t] slice for this b
    float acc = 0.f;
    #pragma unroll 16
    for (int e = 0; e < 64; ++e) {
        float v = arow[e] + htb[e * 128 + t];   // coalesced over t
        acc = fmaf(fmaxf(v, 0.f), w2s[e], acc);
    }
    float out = acc + b2[0];
    X[r * 128 + t] = out;

    // block max over 128 threads (2 waves)
    float mx = out;
    #pragma unroll
    for (int off = 32; off; off >>= 1) mx = fmaxf(mx, __shfl_down(mx, off));
    __shared__ float wm[2];
    if ((t & 63) == 0) wm[t >> 6] = mx;
    __syncthreads();
    if (t == 0) {
        float bm = fmaxf(wm[0], wm[1]);
        if (f == 0) atomicMaxFloat(&Mdep[b * 8 + m], bm);
        else        atomicMaxFloat(&Moth[b * 128 + f], bm);
    }
}

// ---------------------------------------------------------------------------
// Kernel C: exp(x - max), then 10 alternating normalizations.
// 32 blocks (one per (b,m)) x 1024 threads; thread holds a 4x4 register tile.
// Cross-block coupling is ONLY among the 8 blocks sharing batch b, and ONLY
// through the S partial sums. Custom per-(iter,batch) arrival counter replaces
// grid.sync: all data moves via device-scope atomics (coherent cross-XCD),
// __syncthreads' vmcnt(0) drain orders partial-publishes before the counter
// bump, so everything is RELAXED — zero cache-maintenance instructions.
// ---------------------------------------------------------------------------
__global__ __launch_bounds__(1024) void softassign_kernel(
        float* __restrict__ X, const float* __restrict__ Mdep,
        const float* __restrict__ Moth, float* __restrict__ S,
        unsigned* __restrict__ cnt) {
    int blk = blockIdx.x;                  // 0..31 == b*8+m
    int b = blk >> 3;
    int tid = threadIdx.x;
    int tf = tid >> 5, tt = tid & 31;      // 32x32 thread grid, 4x4 tiles
    float* base = X + blk * 16384;

    float x[4][4];
    #pragma unroll
    for (int r = 0; r < 4; ++r) {
        float4 v = *(const float4*)(base + (4 * tf + r) * 128 + 4 * tt);
        x[r][0] = v.x; x[r][1] = v.y; x[r][2] = v.z; x[r][3] = v.w;
    }

    // exp(x - groupmax)
    float mdep = Mdep[blk];
    #pragma unroll
    for (int r = 0; r < 4; ++r) {
        int f = 4 * tf + r;
        float M = (f == 0) ? mdep : Moth[b * 128 + f];
        #pragma unroll
        for (int c = 0; c < 4; ++c) x[r][c] = expf(x[r][c] - M);
    }

    __shared__ float part[128][33];        // +1 pad: conflict-free reduce
    __shared__ float dnm[128];
    __shared__ float depot;

    for (int k = 0; k < 10; ++k) {
        // clamp (reference: maximum(output, EPS) BEFORE the sums)
        #pragma unroll
        for (int r = 0; r < 4; ++r)
            #pragma unroll
            for (int c = 0; c < 4; ++c) x[r][c] = fmaxf(x[r][c], EPSF);

        int dir = k & 1;
        if (dir == 0) {      // per-row partials: part[f][tt]
            #pragma unroll
            for (int r = 0; r < 4; ++r)
                part[4 * tf + r][tt] = x[r][0] + x[r][1] + x[r][2] + x[r][3];
        } else {             // per-col partials: part[t][tf]
            #pragma unroll
            for (int c = 0; c < 4; ++c)
                part[4 * tt + c][tf] = x[0][c] + x[1][c] + x[2][c] + x[3][c];
        }
        __syncthreads();
        float* Scur = &S[(k * 4 + b) * 128];
        if (tid < 128) {     // reduce 32 partials; tid = f (even k) or t (odd k)
            float s = 0.f;
            #pragma unroll 8
            for (int j = 0; j < 32; ++j) s += part[tid][j];
            if (tid == 0) depot = s;                 // block-local group
            else atomicAdd(&Scur[tid], s);           // cross-block (over m)
        }
        // __syncthreads drains vmcnt(0): partial atomicAdds are globally
        // visible before any thread proceeds to the counter bump.
        __syncthreads();
        unsigned* ccur = &cnt[k * 4 + b];
        if (tid == 0) {
            __hip_atomic_fetch_add(ccur, 1u, __ATOMIC_RELAXED,
                                   __HIP_MEMORY_SCOPE_AGENT);
            while (__hip_atomic_load(ccur, __ATOMIC_RELAXED,
                                     __HIP_MEMORY_SCOPE_AGENT) < 8u)
                __builtin_amdgcn_s_sleep(1);
        }
        __syncthreads();

        // stage denominators to LDS (atomic loads bypass stale caches)
        if (tid < 128) {
            dnm[tid] = (tid == 0) ? depot
                : __hip_atomic_load(&Scur[tid], __ATOMIC_RELAXED,
                                    __HIP_MEMORY_SCOPE_AGENT);
        }
        __syncthreads();

        if (dir == 0) {
            #pragma unroll
            for (int r = 0; r < 4; ++r) {
                float inv = 1.f / dnm[4 * tf + r];
                #pragma unroll
                for (int c = 0; c < 4; ++c) x[r][c] *= inv;
            }
        } else {
            #pragma unroll
            for (int c = 0; c < 4; ++c) {
                float inv = 1.f / dnm[4 * tt + c];
                #pragma unroll
                for (int r = 0; r < 4; ++r) x[r][c] *= inv;
            }
        }
    }

    #pragma unroll
    for (int r = 0; r < 4; ++r) {
        float4 v = make_float4(x[r][0], x[r][1], x[r][2], x[r][3]);
        *(float4*)(base + (4 * tf + r) * 128 + 4 * tt) = v;
    }
}

// ---------------------------------------------------------------------------
extern "C" void kernel_launch(void* const* d_in, const int* in_sizes, int n_in,
                              void* d_out, int out_size, void* d_ws, size_t ws_size,
                              hipStream_t stream) {
    const float* cities = (const float*)d_in[0];  // (4,128,64)
    const float* groups = (const float*)d_in[1];  // (4,8,64)
    const float* W1     = (const float*)d_in[2];  // (192,64)
    const float* b1     = (const float*)d_in[3];  // (64,)
    const float* W2     = (const float*)d_in[4];  // (64,1)
    const float* b2     = (const float*)d_in[5];  // (1,)
    float* X  = (float*)d_out;                    // (4,8,128,128)
    float* ws = (float*)d_ws;

    float*    hg   = ws;            // 2048
    float*    hf   = ws + 2048;     // 32768
    float*    htT  = ws + 34816;    // 32768
    float*    S    = ws + 67584;    // 10*4*128 = 5120
    float*    Mbuf = ws + 72704;    // Mdep(32) | Moth(512)
    float*    Mdep = Mbuf;
    float*    Moth = Mbuf + 32;
    unsigned* cnt  = (unsigned*)(ws + 73248);  // 40 arrival counters

    prep_kernel<<<137, 256, 0, stream>>>(cities, groups, W1, hg, hf, htT,
                                         S, Mbuf, cnt);
    mlp_kernel<<<4096, 128, 0, stream>>>(hg, hf, htT, b1, W2, b2, X, Mdep, Moth);
    softassign_kernel<<<32, 1024, 0, stream>>>(X, Mdep, Moth, S, cnt);
}

// Round 3
// 102.676 us; speedup vs baseline: 1.5665x; 1.0282x over previous
//
#include <hip/hip_runtime.h>
#include <math.h>

#define EPSF 1e-8f

// float atomic max via int punning (standard trick, handles mixed signs)
__device__ __forceinline__ void atomicMaxFloat(float* addr, float val) {
    if (val >= 0.f) atomicMax((int*)addr, __float_as_int(val));
    else            atomicMin((unsigned int*)addr, __float_as_uint(val));
}

// ---------------------------------------------------------------------------
// Kernel A: small GEMMs (hf = cities@Wf, htT = (cities@Wt)^T, hg = groups@Wg)
// plus zero/init of the global accumulators + barrier counters.
//   blocks 0..127   : hf + htT   (32768 threads: one (b,f,e) each)
//   blocks 128..135 : hg         (2048 threads)
//   block  136      : zero S[10][4][128], cnt[40]; init Mdep(32)+Moth(512)=-inf
// ---------------------------------------------------------------------------
__global__ __launch_bounds__(256) void prep_kernel(
        const float* __restrict__ cities, const float* __restrict__ groups,
        const float* __restrict__ W1,
        float* __restrict__ hg, float* __restrict__ hf, float* __restrict__ htT,
        float* __restrict__ S, float* __restrict__ Mbuf,
        unsigned* __restrict__ cnt) {
    int blk = blockIdx.x, tid = threadIdx.x;
    if (blk < 128) {
        int gid = blk * 256 + tid;          // 0..32767
        int e = gid & 63;
        int f = (gid >> 6) & 127;
        int b = gid >> 13;
        const float* crow = cities + (b * 128 + f) * 64;
        float af = 0.f, at = 0.f;
        #pragma unroll 8
        for (int d = 0; d < 64; ++d) {
            float c = crow[d];                        // wave-uniform (broadcast)
            af = fmaf(c, W1[(64  + d) * 64 + e], af); // coalesced over e
            at = fmaf(c, W1[(128 + d) * 64 + e], at);
        }
        hf [(b * 128 + f) * 64 + e] = af;   // [b][f][e]
        htT[(b * 64  + e) * 128 + f] = at;  // [b][e][t]  (transposed for kernel B)
    } else if (blk < 136) {
        int gid = (blk - 128) * 256 + tid;  // 0..2047
        int e = gid & 63;
        int m = (gid >> 6) & 7;
        int b = gid >> 9;
        const float* grow = groups + (b * 8 + m) * 64;
        float a = 0.f;
        #pragma unroll 8
        for (int d = 0; d < 64; ++d)
            a = fmaf(grow[d], W1[d * 64 + e], a);
        hg[(b * 8 + m) * 64 + e] = a;
    } else {
        for (int i = tid; i < 5120; i += 256) S[i] = 0.f;
        for (int i = tid; i < 544;  i += 256) Mbuf[i] = -INFINITY;
        if (tid < 40) cnt[tid] = 0u;
    }
}

// ---------------------------------------------------------------------------
// Kernel B (tiled): out[b,m,f,t] = b2 + sum_e W2[e]*relu(hg+hf+ht+b1)
// 512 blocks = (b,m,fgroup-of-8) x 256 threads. htT[b] (64x128, 32 KB) is
// staged ONCE per block in LDS and reused across 8 f-rows -> L2 traffic
// 134 MB -> 17 MB vs the untiled version. Per-thread 4-output tile; f-row
// operands come from one wave-uniform ds_read_b128 broadcast per e.
// Maxes: f==0 -> Mdep[b*8+m] (per-(b,m) over t); f>=1 -> Moth[b*128+f]
// (per-(b,f) over m,t via atomics).
// ---------------------------------------------------------------------------
__global__ __launch_bounds__(256) void mlp_kernel(
        const float* __restrict__ hg, const float* __restrict__ hf,
        const float* __restrict__ htT,
        const float* __restrict__ b1, const float* __restrict__ W2,
        const float* __restrict__ b2,
        float* __restrict__ X, float* __restrict__ Mdep, float* __restrict__ Moth) {
    int blk = blockIdx.x;                  // (b*8+m)*16 + fg
    int fg  = blk & 15;
    int bm  = blk >> 4;                    // 0..31
    int b   = bm >> 3;
    int tid = threadIdx.x;                 // 0..255

    __shared__ float hts[64][128];         // 32 KB: htT[b] slice [e][t]
    __shared__ float arowT[64][8];         // [e][f8]: hg+hf+b1 (16B-aligned rows)
    __shared__ float w2s[64];
    __shared__ float wmax[4][4];           // [wave][i] partial maxes

    // stage htT[b]: 2048 float4, 8 per thread, coalesced
    {
        const float4* src = (const float4*)(htT + b * 8192);
        float4* dst = (float4*)(&hts[0][0]);
        #pragma unroll
        for (int i = 0; i < 8; ++i) dst[tid + 256 * i] = src[tid + 256 * i];
    }
    // stage arowT (512 values, 2 per thread) + w2s
    #pragma unroll
    for (int j = 0; j < 2; ++j) {
        int v = tid + 256 * j;             // 0..511
        int e = v >> 3, f8 = v & 7;
        int f = fg * 8 + f8;
        arowT[e][f8] = hg[bm * 64 + e] + hf[(b * 128 + f) * 64 + e] + b1[e];
    }
    if (tid < 64) w2s[tid] = W2[tid];
    __syncthreads();

    int t  = tid & 127;                    // column
    int fo = tid >> 7;                     // 0..1 -> f8 = fo*4+i
    float acc[4] = {0.f, 0.f, 0.f, 0.f};
    #pragma unroll 8
    for (int e = 0; e < 64; ++e) {
        float ht = hts[e][t];              // 2-way bank alias: free
        float w2 = w2s[e];                 // broadcast
        float4 ar = *(const float4*)(&arowT[e][fo * 4]);  // b128 broadcast
        acc[0] = fmaf(fmaxf(ar.x + ht, 0.f), w2, acc[0]);
        acc[1] = fmaf(fmaxf(ar.y + ht, 0.f), w2, acc[1]);
        acc[2] = fmaf(fmaxf(ar.z + ht, 0.f), w2, acc[2]);
        acc[3] = fmaf(fmaxf(ar.w + ht, 0.f), w2, acc[3]);
    }

    float b2v = b2[0];
    float fmax4[4];
    #pragma unroll
    for (int i = 0; i < 4; ++i) {
        float out = acc[i] + b2v;
        int f = fg * 8 + fo * 4 + i;
        X[(bm * 128 + f) * 128 + t] = out;  // coalesced over t
        fmax4[i] = out;
    }

    // per-f max: shuffle over 64 lanes (half the t-range), combine wave pairs
    #pragma unroll
    for (int i = 0; i < 4; ++i)
        #pragma unroll
        for (int off = 32; off; off >>= 1)
            fmax4[i] = fmaxf(fmax4[i], __shfl_down(fmax4[i], off));
    int wv = tid >> 6;                     // wave 0..3
    if ((tid & 63) == 0) {
        #pragma unroll
        for (int i = 0; i < 4; ++i) wmax[wv][i] = fmax4[i];
    }
    __syncthreads();
    if (tid < 8) {                         // tid = f8
        int w0 = (tid >> 2) * 2, i = tid & 3;
        float m = fmaxf(wmax[w0][i], wmax[w0 + 1][i]);
        int f = fg * 8 + tid;
        if (f == 0) atomicMaxFloat(&Mdep[bm], m);        // only fg==0 block
        else        atomicMaxFloat(&Moth[b * 128 + f], m);
    }
}

// ---------------------------------------------------------------------------
// Kernel C: exp(x - max), then 10 alternating normalizations.
// 32 blocks (one per (b,m)) x 1024 threads; thread holds a 4x4 register tile.
// Cross-block coupling is ONLY among the 8 blocks sharing batch b, through
// the S partial sums; custom per-(iter,batch) arrival counter replaces
// grid.sync (all data via device-scope atomics; __syncthreads' vmcnt(0)
// drain orders partial-publishes before the counter bump -> all RELAXED).
// ---------------------------------------------------------------------------
__global__ __launch_bounds__(1024) void softassign_kernel(
        float* __restrict__ X, const float* __restrict__ Mdep,
        const float* __restrict__ Moth, float* __restrict__ S,
        unsigned* __restrict__ cnt) {
    int blk = blockIdx.x;                  // 0..31 == b*8+m
    int b = blk >> 3;
    int tid = threadIdx.x;
    int tf = tid >> 5, tt = tid & 31;      // 32x32 thread grid, 4x4 tiles
    float* base = X + blk * 16384;

    float x[4][4];
    #pragma unroll
    for (int r = 0; r < 4; ++r) {
        float4 v = *(const float4*)(base + (4 * tf + r) * 128 + 4 * tt);
        x[r][0] = v.x; x[r][1] = v.y; x[r][2] = v.z; x[r][3] = v.w;
    }

    // exp(x - groupmax)
    float mdep = Mdep[blk];
    #pragma unroll
    for (int r = 0; r < 4; ++r) {
        int f = 4 * tf + r;
        float M = (f == 0) ? mdep : Moth[b * 128 + f];
        #pragma unroll
        for (int c = 0; c < 4; ++c) x[r][c] = expf(x[r][c] - M);
    }

    __shared__ float part[128][33];        // +1 pad: conflict-free reduce
    __shared__ float dnm[128];
    __shared__ float depot;

    for (int k = 0; k < 10; ++k) {
        // clamp (reference: maximum(output, EPS) BEFORE the sums)
        #pragma unroll
        for (int r = 0; r < 4; ++r)
            #pragma unroll
            for (int c = 0; c < 4; ++c) x[r][c] = fmaxf(x[r][c], EPSF);

        int dir = k & 1;
        if (dir == 0) {      // per-row partials: part[f][tt]
            #pragma unroll
            for (int r = 0; r < 4; ++r)
                part[4 * tf + r][tt] = x[r][0] + x[r][1] + x[r][2] + x[r][3];
        } else {             // per-col partials: part[t][tf]
            #pragma unroll
            for (int c = 0; c < 4; ++c)
                part[4 * tt + c][tf] = x[0][c] + x[1][c] + x[2][c] + x[3][c];
        }
        __syncthreads();
        float* Scur = &S[(k * 4 + b) * 128];
        if (tid < 128) {     // reduce 32 partials; tid = f (even k) or t (odd k)
            float s = 0.f;
            #pragma unroll 8
            for (int j = 0; j < 32; ++j) s += part[tid][j];
            if (tid == 0) depot = s;                 // block-local group
            else atomicAdd(&Scur[tid], s);           // cross-block (over m)
        }
        // __syncthreads drains vmcnt(0): partial atomicAdds are globally
        // visible before any thread proceeds to the counter bump.
        __syncthreads();
        unsigned* ccur = &cnt[k * 4 + b];
        if (tid == 0) {
            __hip_atomic_fetch_add(ccur, 1u, __ATOMIC_RELAXED,
                                   __HIP_MEMORY_SCOPE_AGENT);
            while (__hip_atomic_load(ccur, __ATOMIC_RELAXED,
                                     __HIP_MEMORY_SCOPE_AGENT) < 8u)
                __builtin_amdgcn_s_sleep(1);
        }
        __syncthreads();

        // stage denominators to LDS (atomic loads bypass stale caches)
        if (tid < 128) {
            dnm[tid] = (tid == 0) ? depot
                : __hip_atomic_load(&Scur[tid], __ATOMIC_RELAXED,
                                    __HIP_MEMORY_SCOPE_AGENT);
        }
        __syncthreads();

        if (dir == 0) {
            #pragma unroll
            for (int r = 0; r < 4; ++r) {
                float inv = 1.f / dnm[4 * tf + r];
                #pragma unroll
                for (int c = 0; c < 4; ++c) x[r][c] *= inv;
            }
        } else {
            #pragma unroll
            for (int c = 0; c < 4; ++c) {
                float inv = 1.f / dnm[4 * tt + c];
                #pragma unroll
                for (int r = 0; r < 4; ++r) x[r][c] *= inv;
            }
        }
    }

    #pragma unroll
    for (int r = 0; r < 4; ++r) {
        float4 v = make_float4(x[r][0], x[r][1], x[r][2], x[r][3]);
        *(float4*)(base + (4 * tf + r) * 128 + 4 * tt) = v;
    }
}

// ---------------------------------------------------------------------------
extern "C" void kernel_launch(void* const* d_in, const int* in_sizes, int n_in,
                              void* d_out, int out_size, void* d_ws, size_t ws_size,
                              hipStream_t stream) {
    const float* cities = (const float*)d_in[0];  // (4,128,64)
    const float* groups = (const float*)d_in[1];  // (4,8,64)
    const float* W1     = (const float*)d_in[2];  // (192,64)
    const float* b1     = (const float*)d_in[3];  // (64,)
    const float* W2     = (const float*)d_in[4];  // (64,1)
    const float* b2     = (const float*)d_in[5];  // (1,)
    float* X  = (float*)d_out;                    // (4,8,128,128)
    float* ws = (float*)d_ws;

    float*    hg   = ws;            // 2048
    float*    hf   = ws + 2048;     // 32768
    float*    htT  = ws + 34816;    // 32768
    float*    S    = ws + 67584;    // 10*4*128 = 5120
    float*    Mbuf = ws + 72704;    // Mdep(32) | Moth(512)
    float*    Mdep = Mbuf;
    float*    Moth = Mbuf + 32;
    unsigned* cnt  = (unsigned*)(ws + 73248);  // 40 arrival counters

    prep_kernel<<<137, 256, 0, stream>>>(cities, groups, W1, hg, hf, htT,
                                         S, Mbuf, cnt);
    mlp_kernel<<<512, 256, 0, stream>>>(hg, hf, htT, b1, W2, b2, X, Mdep, Moth);
    softassign_kernel<<<32, 1024, 0, stream>>>(X, Mdep, Moth, S, cnt);
}